// Round 1
// baseline (79.599 us; speedup 1.0000x reference)
//
#include <hip/hip_runtime.h>

// CenterLoss: loss = ( sum_i clamp(|x_i - c_{label_i}|^2, 1e-12, 1e12)
//                      + B*(C-1)*1e-12 ) / B
// B=16384, C=1000, D=512. Pure gather + reduction; no GEMM needed since the
// one-hot mask kills all off-label distmat entries (they contribute 1e-12
// each after the post-mask clamp).

#define B_ROWS    16384
#define C_CLASSES 1000
#define D_DIM     512
#define S1_BLOCKS 1024

__global__ __launch_bounds__(256) void center_loss_stage1(
    const float* __restrict__ x,
    const int*   __restrict__ labels,
    const float* __restrict__ centers,
    float*       __restrict__ partials)
{
    const int tid   = threadIdx.x;
    const int wave  = tid >> 6;        // 4 waves per block
    const int lane  = tid & 63;
    const int gwave = blockIdx.x * 4 + wave;
    const int nwaves = gridDim.x * 4;  // 4096 waves -> 4 rows per wave

    float waveAcc = 0.0f;

    for (int row = gwave; row < B_ROWS; row += nwaves) {
        const int lab = labels[row];
        const float4* __restrict__ xr =
            (const float4*)(x + (size_t)row * D_DIM);
        const float4* __restrict__ cr =
            (const float4*)(centers + (size_t)lab * D_DIM);

        // 512 floats = 128 float4 per row; 64 lanes * 2 coalesced float4 loads
        float4 xa = xr[lane];
        float4 xb = xr[lane + 64];
        float4 ca = cr[lane];
        float4 cb = cr[lane + 64];

        float d0 = xa.x - ca.x, d1 = xa.y - ca.y;
        float d2 = xa.z - ca.z, d3 = xa.w - ca.w;
        float e0 = xb.x - cb.x, e1 = xb.y - cb.y;
        float e2 = xb.z - cb.z, e3 = xb.w - cb.w;

        float s = d0*d0 + d1*d1 + d2*d2 + d3*d3
                + e0*e0 + e1*e1 + e2*e2 + e3*e3;

        // wave-64 reduction
        #pragma unroll
        for (int off = 32; off > 0; off >>= 1)
            s += __shfl_down(s, off, 64);

        if (lane == 0) {
            // reference clamps the (masked) per-entry distance
            s = fminf(fmaxf(s, 1e-12f), 1e12f);
            waveAcc += s;
        }
    }

    __shared__ float lds[4];
    if (lane == 0) lds[wave] = waveAcc;
    __syncthreads();
    if (tid == 0)
        partials[blockIdx.x] = lds[0] + lds[1] + lds[2] + lds[3];
}

__global__ __launch_bounds__(256) void center_loss_stage2(
    const float* __restrict__ partials,
    float*       __restrict__ out)
{
    const int tid  = threadIdx.x;
    const int wave = tid >> 6;
    const int lane = tid & 63;

    float s = 0.0f;
    for (int i = tid; i < S1_BLOCKS; i += 256)
        s += partials[i];

    #pragma unroll
    for (int off = 32; off > 0; off >>= 1)
        s += __shfl_down(s, off, 64);

    __shared__ float lds[4];
    if (lane == 0) lds[wave] = s;
    __syncthreads();
    if (tid == 0) {
        float tot = lds[0] + lds[1] + lds[2] + lds[3];
        // masked-out zeros clamp up to 1e-12: B*(C-1) of them
        tot += (float)B_ROWS * (float)(C_CLASSES - 1) * 1e-12f;
        out[0] = tot / (float)B_ROWS;
    }
}

extern "C" void kernel_launch(void* const* d_in, const int* in_sizes, int n_in,
                              void* d_out, int out_size, void* d_ws, size_t ws_size,
                              hipStream_t stream) {
    const float* x       = (const float*)d_in[0];
    const int*   labels  = (const int*)d_in[1];
    const float* centers = (const float*)d_in[2];
    float*       out     = (float*)d_out;
    float*       partials = (float*)d_ws;   // S1_BLOCKS floats = 4 KB

    center_loss_stage1<<<S1_BLOCKS, 256, 0, stream>>>(x, labels, centers, partials);
    center_loss_stage2<<<1, 256, 0, stream>>>(partials, out);
}